// Round 6
// baseline (158.673 us; speedup 1.0000x reference)
//
#include <hip/hip_runtime.h>
#include <math.h>

// PillarFeatureNet, single fused persistent kernel.
//
//  h[m,p,o] = dot(v_p, ABCD_o) + E0[m][o]   (E0 point-independent)
//  R[m][o]  = max_p dot + E0  is BN-independent; s_o>0 =>
//  out = relu(s*R + b), with s,b from 9-vec + 9x9 feature moments.
//
//  Phase 1: each wave owns pillar-pairs (10 fixed iters, stride 2048 waves):
//           moments (lane=point) + R (lane=channel, points re-read via
//           wave-local LDS broadcast). Block-reduce moments -> 54 global
//           atomicAdds.
//  Grid barrier (agent-scope atomics, counter memset to 0 pre-launch).
//  Phase 2: every block redundantly computes scale/bias from gstats.
//  Phase 3: grid-stride float4 apply: out = relu(s*R + b).

#define PP    32
#define OUTC  64
#define GRID  512
#define BLK   256
#define NWAVE (GRID * (BLK / 64))   // 2048 waves
#define ITERS 10                    // ceil((40000/2) / 2048)

static constexpr float VX = 0.2f, VY = 0.2f;
static constexpr float X0 = -51.2f, Y0 = -51.2f;
static constexpr float BNEPS = 1e-3f;

__global__ __launch_bounds__(BLK, 2) void pfn_fused(
    const float4* __restrict__ vox, const int4* __restrict__ coords,
    const int* __restrict__ npts, const float* __restrict__ W,
    const float* __restrict__ gamma, const float* __restrict__ beta,
    unsigned* __restrict__ cnt, float* __restrict__ gstats,
    float* __restrict__ R, float* __restrict__ out, int M, float invN)
{
    const int tid  = threadIdx.x;
    const int lane = tid & 63;
    const int wv   = tid >> 6;
    const int q    = lane & 31;     // point within pillar-half
    const int hf   = lane >> 5;     // 0 = pillar A, 1 = pillar B

    __shared__ float4 sv[BLK];                       // per-wave 64-point stash
    __shared__ float  red[BLK / 64][54];
    __shared__ float  tot[54];
    __shared__ __align__(16) float sS[OUTC];
    __shared__ __align__(16) float sB[OUTC];

    // per-lane channel weights (lane = o)
    float w4, w5, w6, w7, w8, Ac, Bc, Cc, Dc;
    {
        const float w0 = W[0 * OUTC + lane], w1 = W[1 * OUTC + lane];
        const float w2 = W[2 * OUTC + lane], w3 = W[3 * OUTC + lane];
        w4 = W[4 * OUTC + lane]; w5 = W[5 * OUTC + lane];
        w6 = W[6 * OUTC + lane]; w7 = W[7 * OUTC + lane];
        w8 = W[8 * OUTC + lane];
        Ac = w0 + w4 + w7; Bc = w1 + w5 + w8; Cc = w2 + w6; Dc = w3;
    }

    float acc[54];
#pragma unroll
    for (int k = 0; k < 54; ++k) acc[k] = 0.f;

    const int pairs = M >> 1;                       // M even (40000)
    const int wid   = blockIdx.x * (BLK / 64) + wv;

#pragma unroll 1
    for (int it = 0; it < ITERS; ++it) {
        const int pr = wid + it * NWAVE;
        if (pr < pairs) {                           // wave-uniform branch
            const int p  = pr * 2 + hf;
            const float4 v  = vox[(size_t)p * PP + q];
            const int    n0 = npts[p];
            const int4   cd = coords[p];

            // per-pillar xyz mean (32-lane xor reduce stays in half-wave)
            float sx = v.x, sy = v.y, sz = v.z;
#pragma unroll
            for (int mk = 16; mk >= 1; mk >>= 1) {
                sx += __shfl_xor(sx, mk);
                sy += __shfl_xor(sy, mk);
                sz += __shfl_xor(sz, mk);
            }
            const int   np  = n0 < 1 ? 1 : n0;
            const float inv = 1.f / (float)np;
            const float mx = sx * inv, my = sy * inv, mz = sz * inv;
            const float px = (float)cd.w * VX + X0;
            const float py = (float)cd.z * VY + Y0;

            // feature moments (lane = point)
            {
                float f[9];
                f[0] = v.x; f[1] = v.y; f[2] = v.z; f[3] = v.w;
                f[4] = v.x - mx; f[5] = v.y - my; f[6] = v.z - mz;
                f[7] = v.x - px; f[8] = v.y - py;
#pragma unroll
                for (int i = 0; i < 9; ++i) acc[i] += f[i];
                int k = 9;
#pragma unroll
                for (int i = 0; i < 9; ++i) {
#pragma unroll
                    for (int j = i; j < 9; ++j) acc[k++] += f[i] * f[j];
                }
            }

            // stash the pair's 64 points (wave-local LDS; no block barrier)
            sv[wv * 64 + lane] = v;

            // broadcast per-pillar E0 inputs to all lanes
            const float mxA = __shfl(mx, 0),  myA = __shfl(my, 0),  mzA = __shfl(mz, 0);
            const float pxA = __shfl(px, 0),  pyA = __shfl(py, 0);
            const float mxB = __shfl(mx, 32), myB = __shfl(my, 32), mzB = __shfl(mz, 32);
            const float pxB = __shfl(px, 32), pyB = __shfl(py, 32);

            // lane = channel: 4 independent max chains per pillar
            const float4* sp = &sv[wv * 64];
            float g0 = -INFINITY, g1 = -INFINITY, g2 = -INFINITY, g3 = -INFINITY;
            float h0 = -INFINITY, h1 = -INFINITY, h2 = -INFINITY, h3 = -INFINITY;
#pragma unroll
            for (int pt = 0; pt < PP; pt += 4) {
                const float4 a0 = sp[pt],     a1 = sp[pt + 1];
                const float4 a2 = sp[pt + 2], a3 = sp[pt + 3];
                float t;
                t = fmaf(a0.x, Ac, fmaf(a0.y, Bc, fmaf(a0.z, Cc, a0.w * Dc)));
                g0 = fmaxf(g0, t);
                t = fmaf(a1.x, Ac, fmaf(a1.y, Bc, fmaf(a1.z, Cc, a1.w * Dc)));
                g1 = fmaxf(g1, t);
                t = fmaf(a2.x, Ac, fmaf(a2.y, Bc, fmaf(a2.z, Cc, a2.w * Dc)));
                g2 = fmaxf(g2, t);
                t = fmaf(a3.x, Ac, fmaf(a3.y, Bc, fmaf(a3.z, Cc, a3.w * Dc)));
                g3 = fmaxf(g3, t);
            }
#pragma unroll
            for (int pt = 0; pt < PP; pt += 4) {
                const float4 b0 = sp[PP + pt],     b1 = sp[PP + pt + 1];
                const float4 b2 = sp[PP + pt + 2], b3 = sp[PP + pt + 3];
                float t;
                t = fmaf(b0.x, Ac, fmaf(b0.y, Bc, fmaf(b0.z, Cc, b0.w * Dc)));
                h0 = fmaxf(h0, t);
                t = fmaf(b1.x, Ac, fmaf(b1.y, Bc, fmaf(b1.z, Cc, b1.w * Dc)));
                h1 = fmaxf(h1, t);
                t = fmaf(b2.x, Ac, fmaf(b2.y, Bc, fmaf(b2.z, Cc, b2.w * Dc)));
                h2 = fmaxf(h2, t);
                t = fmaf(b3.x, Ac, fmaf(b3.y, Bc, fmaf(b3.z, Cc, b3.w * Dc)));
                h3 = fmaxf(h3, t);
            }

            const float E0A = -(mxA * w4 + myA * w5 + mzA * w6 + pxA * w7 + pyA * w8);
            const float E0B = -(mxB * w4 + myB * w5 + mzB * w6 + pxB * w7 + pyB * w8);
            const int pA = pr * 2;
            R[(size_t)pA * OUTC + lane]       = fmaxf(fmaxf(g0, g1), fmaxf(g2, g3)) + E0A;
            R[(size_t)(pA + 1) * OUTC + lane] = fmaxf(fmaxf(h0, h1), fmaxf(h2, h3)) + E0B;
        }
    }

    // ---- block moment reduction -> 54 device-scope atomic adds ----
#pragma unroll
    for (int k = 0; k < 54; ++k) {
        float a = acc[k];
#pragma unroll
        for (int mk = 32; mk >= 1; mk >>= 1) a += __shfl_xor(a, mk);
        acc[k] = a;
    }
    if (lane == 0) {
#pragma unroll
        for (int k = 0; k < 54; ++k) red[wv][k] = acc[k];
    }
    __syncthreads();
    if (tid < 54) {
        float t = red[0][tid] + red[1][tid] + red[2][tid] + red[3][tid];
        atomicAdd(&gstats[tid], t);               // device scope by default
    }

    // ---- grid barrier (counter pre-zeroed by hipMemsetAsync) ----
    __threadfence();                              // flush this thread's R writes
    __syncthreads();
    if (tid == 0) {
        __hip_atomic_fetch_add(cnt, 1u, __ATOMIC_ACQ_REL, __HIP_MEMORY_SCOPE_AGENT);
        while (__hip_atomic_load(cnt, __ATOMIC_ACQUIRE, __HIP_MEMORY_SCOPE_AGENT)
               < (unsigned)GRID) {
            __builtin_amdgcn_s_sleep(1);
        }
    }
    __syncthreads();

    // ---- every block: finalize scale/bias from global moments ----
    if (tid < 54) {
        tot[tid] = __hip_atomic_load(&gstats[tid], __ATOMIC_RELAXED,
                                     __HIP_MEMORY_SCOPE_AGENT);
    }
    __syncthreads();
    if (tid < OUTC) {
        float w[9];
#pragma unroll
        for (int c = 0; c < 9; ++c) w[c] = W[c * OUTC + tid];
        float mean = 0.f;
#pragma unroll
        for (int c = 0; c < 9; ++c) mean += (tot[c] * invN) * w[c];
        float ex2 = 0.f;
        int k = 9;
#pragma unroll
        for (int i = 0; i < 9; ++i) {
#pragma unroll
            for (int j = i; j < 9; ++j) {
                const float qv = tot[k++] * invN;
                ex2 += ((i == j) ? 1.f : 2.f) * qv * w[i] * w[j];
            }
        }
        const float var = ex2 - mean * mean;
        const float sc  = gamma[tid] * rsqrtf(var + BNEPS);
        sS[tid] = sc;
        sB[tid] = beta[tid] - mean * sc;
    }
    __syncthreads();

    // ---- apply: out = relu(s*R + b), grid-stride float4, og fixed/thread ----
    const int n4 = M * (OUTC / 4);
    const int i0 = blockIdx.x * BLK + tid;
    const int og = i0 & (OUTC / 4 - 1);
    const float4 s4 = *reinterpret_cast<const float4*>(&sS[og * 4]);
    const float4 b4 = *reinterpret_cast<const float4*>(&sB[og * 4]);
    const float4* __restrict__ R4 = reinterpret_cast<const float4*>(R);
    float4* __restrict__ out4     = reinterpret_cast<float4*>(out);
    for (int i = i0; i < n4; i += GRID * BLK) {
        const float4 r = R4[i];
        float4 o;
        o.x = fmaxf(fmaf(s4.x, r.x, b4.x), 0.f);
        o.y = fmaxf(fmaf(s4.y, r.y, b4.y), 0.f);
        o.z = fmaxf(fmaf(s4.z, r.z, b4.z), 0.f);
        o.w = fmaxf(fmaf(s4.w, r.w, b4.w), 0.f);
        out4[i] = o;
    }
}

// ---------------------------------------------------------------------------
extern "C" void kernel_launch(void* const* d_in, const int* in_sizes, int n_in,
                              void* d_out, int out_size, void* d_ws, size_t ws_size,
                              hipStream_t stream)
{
    const float* voxels = (const float*)d_in[0];
    const int*   coords = (const int*)d_in[1];
    const int*   npts   = (const int*)d_in[2];
    const float* W      = (const float*)d_in[3];
    const float* gamma  = (const float*)d_in[4];
    const float* beta   = (const float*)d_in[5];
    float*       out    = (float*)d_out;

    const int M = in_sizes[0] / (PP * 4);   // voxels is (M, P, 4); M even

    // ws layout (bytes): [0] counter | [64] gstats (54 f) | [512] R (M*64 f)
    unsigned* cnt    = (unsigned*)d_ws;
    float*    gstats = (float*)((char*)d_ws + 64);
    float*    R      = (float*)((char*)d_ws + 512);

    hipMemsetAsync(d_ws, 0, 512, stream);   // zero counter + gstats (captured)

    pfn_fused<<<GRID, BLK, 0, stream>>>((const float4*)voxels,
                                        (const int4*)coords, npts, W, gamma,
                                        beta, cnt, gstats, R, out, M,
                                        1.f / (float)(M * PP));
}

// Round 8
// 118.076 us; speedup vs baseline: 1.3438x; 1.3438x over previous
//
#include <hip/hip_runtime.h>
#include <math.h>

// PillarFeatureNet, 3-kernel pipeline.
//
//  h[m,p,o] = dot(v_p, ABCD_o) + E0[m][o]     (E0 point-independent)
//  R[m][o]  = max_p dot + E0   is BN-independent; s_o = gamma*rsqrt(var+eps)>0
//  => out = relu(s*R + b).  BN stats from 9 first + 45 second feature moments.
//
//  K1 pfn_main : one pass over voxels; moments (lane=point) + R (lane=channel,
//                points re-read via wave-uniform SCALAR loads -> s_load pipe).
//  K2 pfn_finalize : reduce [54][G1] partials -> per-channel scale/bias.
//  K3 pfn_apply : elementwise relu(s*R+b), 1 float4 per thread.

#define PP   32
#define OUTC 64
#define G1   1024    // K1 grid; 4096 waves (4 waves/SIMD at launch_bounds(,4))
#define B1   256

static constexpr float VX = 0.2f, VY = 0.2f;
static constexpr float X0 = -51.2f, Y0 = -51.2f;
static constexpr float BNEPS = 1e-3f;

// ---------------------------------------------------------------------------
__global__ __launch_bounds__(B1, 4) void pfn_main(
    const float4* __restrict__ vox, const int4* __restrict__ coords,
    const int* __restrict__ npts, const float* __restrict__ W,
    float* __restrict__ partials, float* __restrict__ R, int M)
{
    const int tid  = threadIdx.x;
    const int lane = tid & 63;
    const int wv   = tid >> 6;
    const int q    = lane & 31;     // point within pillar-half
    const int hf   = lane >> 5;     // 0 = pillar A, 1 = pillar B

    // per-lane channel weights (lane = o)
    float w4, w5, w6, w7, w8, Ac, Bc, Cc, Dc;
    {
        const float w0 = W[0 * OUTC + lane], w1 = W[1 * OUTC + lane];
        const float w2 = W[2 * OUTC + lane], w3 = W[3 * OUTC + lane];
        w4 = W[4 * OUTC + lane]; w5 = W[5 * OUTC + lane];
        w6 = W[6 * OUTC + lane]; w7 = W[7 * OUTC + lane];
        w8 = W[8 * OUTC + lane];
        Ac = w0 + w4 + w7; Bc = w1 + w5 + w8; Cc = w2 + w6; Dc = w3;
    }

    float acc[54];
#pragma unroll
    for (int k = 0; k < 54; ++k) acc[k] = 0.f;

    const int pairs = M >> 1;                  // M even (40000)
    const int nwave = G1 * (B1 / 64);          // 4096
    int pr = blockIdx.x * (B1 / 64) + wv;

    // depth-1 prefetch of the per-lane point + pillar metadata
    float4 v  = make_float4(0.f, 0.f, 0.f, 0.f);
    int    np = 1;
    int4   cd = make_int4(0, 0, 0, 0);
    if (pr < pairs) {
        const int p = pr * 2 + hf;
        v = vox[(size_t)p * PP + q];
        np = npts[p];
        cd = coords[p];
    }

    while (pr < pairs) {
        const int prn = pr + nwave;
        float4 vn  = make_float4(0.f, 0.f, 0.f, 0.f);
        int    npn = 1;
        int4   cdn = make_int4(0, 0, 0, 0);
        if (prn < pairs) {
            const int p = prn * 2 + hf;
            vn = vox[(size_t)p * PP + q];
            npn = npts[p];
            cdn = coords[p];
        }

        // ---- phase M: pillar mean + feature moments (lane = point) ----
        float sx = v.x, sy = v.y, sz = v.z;
#pragma unroll
        for (int mk = 16; mk >= 1; mk >>= 1) {
            sx += __shfl_xor(sx, mk);
            sy += __shfl_xor(sy, mk);
            sz += __shfl_xor(sz, mk);
        }
        const int   npc = np < 1 ? 1 : np;
        const float inv = 1.f / (float)npc;
        const float mx = sx * inv, my = sy * inv, mz = sz * inv;
        const float px = (float)cd.w * VX + X0;
        const float py = (float)cd.z * VY + Y0;

        {
            float f[9];
            f[0] = v.x; f[1] = v.y; f[2] = v.z; f[3] = v.w;
            f[4] = v.x - mx; f[5] = v.y - my; f[6] = v.z - mz;
            f[7] = v.x - px; f[8] = v.y - py;
#pragma unroll
            for (int i = 0; i < 9; ++i) acc[i] += f[i];
            int k = 9;
#pragma unroll
            for (int i = 0; i < 9; ++i) {
#pragma unroll
                for (int j = i; j < 9; ++j) acc[k++] += f[i] * f[j];
            }
        }

        // ---- phase R: lane = channel; points via wave-uniform SCALAR loads --
        const int pAu = __builtin_amdgcn_readfirstlane(pr * 2);
        const float* __restrict__ sp = (const float*)(vox + (size_t)pAu * PP);

        float g0 = -INFINITY, g1 = -INFINITY, g2 = -INFINITY, g3 = -INFINITY;
        float h0 = -INFINITY, h1 = -INFINITY, h2 = -INFINITY, h3 = -INFINITY;
#pragma unroll
        for (int pt = 0; pt < PP; pt += 4) {      // pillar A: points 0..31
            const int b = pt * 4;
            float t;
            t = fmaf(sp[b + 0], Ac, fmaf(sp[b + 1], Bc,
                  fmaf(sp[b + 2], Cc, sp[b + 3] * Dc)));
            g0 = fmaxf(g0, t);
            t = fmaf(sp[b + 4], Ac, fmaf(sp[b + 5], Bc,
                  fmaf(sp[b + 6], Cc, sp[b + 7] * Dc)));
            g1 = fmaxf(g1, t);
            t = fmaf(sp[b + 8], Ac, fmaf(sp[b + 9], Bc,
                  fmaf(sp[b + 10], Cc, sp[b + 11] * Dc)));
            g2 = fmaxf(g2, t);
            t = fmaf(sp[b + 12], Ac, fmaf(sp[b + 13], Bc,
                  fmaf(sp[b + 14], Cc, sp[b + 15] * Dc)));
            g3 = fmaxf(g3, t);
        }
#pragma unroll
        for (int pt = 0; pt < PP; pt += 4) {      // pillar B: points 32..63
            const int b = (PP + pt) * 4;
            float t;
            t = fmaf(sp[b + 0], Ac, fmaf(sp[b + 1], Bc,
                  fmaf(sp[b + 2], Cc, sp[b + 3] * Dc)));
            h0 = fmaxf(h0, t);
            t = fmaf(sp[b + 4], Ac, fmaf(sp[b + 5], Bc,
                  fmaf(sp[b + 6], Cc, sp[b + 7] * Dc)));
            h1 = fmaxf(h1, t);
            t = fmaf(sp[b + 8], Ac, fmaf(sp[b + 9], Bc,
                  fmaf(sp[b + 10], Cc, sp[b + 11] * Dc)));
            h2 = fmaxf(h2, t);
            t = fmaf(sp[b + 12], Ac, fmaf(sp[b + 13], Bc,
                  fmaf(sp[b + 14], Cc, sp[b + 15] * Dc)));
            h3 = fmaxf(h3, t);
        }

        // per-pillar E0 inputs broadcast from half-wave roots
        const float mxA = __shfl(mx, 0),  myA = __shfl(my, 0),  mzA = __shfl(mz, 0);
        const float pxA = __shfl(px, 0),  pyA = __shfl(py, 0);
        const float mxB = __shfl(mx, 32), myB = __shfl(my, 32), mzB = __shfl(mz, 32);
        const float pxB = __shfl(px, 32), pyB = __shfl(py, 32);

        const float E0A = -(mxA * w4 + myA * w5 + mzA * w6 + pxA * w7 + pyA * w8);
        const float E0B = -(mxB * w4 + myB * w5 + mzB * w6 + pxB * w7 + pyB * w8);

        const int pA = pr * 2;
        R[(size_t)pA * OUTC + lane]       = fmaxf(fmaxf(g0, g1), fmaxf(g2, g3)) + E0A;
        R[(size_t)(pA + 1) * OUTC + lane] = fmaxf(fmaxf(h0, h1), fmaxf(h2, h3)) + E0B;

        pr = prn; v = vn; np = npn; cd = cdn;
    }

    // ---- moment reduction: 64-lane butterfly, cross-wave via LDS ----
#pragma unroll
    for (int k = 0; k < 54; ++k) {
        float a = acc[k];
#pragma unroll
        for (int mk = 32; mk >= 1; mk >>= 1) a += __shfl_xor(a, mk);
        acc[k] = a;
    }
    __shared__ float red[B1 / 64][54];
    if (lane == 0) {
#pragma unroll
        for (int k = 0; k < 54; ++k) red[wv][k] = acc[k];
    }
    __syncthreads();
    if (tid < 54) {
        float t = red[0][tid] + red[1][tid] + red[2][tid] + red[3][tid];
        partials[tid * G1 + blockIdx.x] = t;    // transposed [k][block]
    }
}

// ---------------------------------------------------------------------------
__global__ __launch_bounds__(256) void pfn_finalize(
    const float* __restrict__ partials, const float* __restrict__ W,
    const float* __restrict__ gamma, const float* __restrict__ beta,
    float* __restrict__ sb, float invN)
{
    const int t = threadIdx.x;
    __shared__ float red[54][4];
    __shared__ float tot[54];

    if (t < 216) {
        const int k = t >> 2, qq = t & 3;
        const float* p = partials + k * G1 + qq * (G1 / 4);
        float s = 0.f;
#pragma unroll 16
        for (int i = 0; i < G1 / 4; ++i) s += p[i];
        red[k][qq] = s;
    }
    __syncthreads();
    if (t < 54) tot[t] = red[t][0] + red[t][1] + red[t][2] + red[t][3];
    __syncthreads();

    if (t < OUTC) {
        float w[9];
#pragma unroll
        for (int c = 0; c < 9; ++c) w[c] = W[c * OUTC + t];
        float mean = 0.f;
#pragma unroll
        for (int c = 0; c < 9; ++c) mean += (tot[c] * invN) * w[c];
        float ex2 = 0.f;
        int k = 9;
#pragma unroll
        for (int i = 0; i < 9; ++i) {
#pragma unroll
            for (int j = i; j < 9; ++j) {
                const float qv = tot[k++] * invN;
                ex2 += ((i == j) ? 1.f : 2.f) * qv * w[i] * w[j];
            }
        }
        const float var = ex2 - mean * mean;
        const float sc  = gamma[t] * rsqrtf(var + BNEPS);
        sb[t]        = sc;
        sb[OUTC + t] = beta[t] - mean * sc;
    }
}

// ---------------------------------------------------------------------------
__global__ __launch_bounds__(256) void pfn_apply(
    const float4* __restrict__ R4, const float* __restrict__ sb,
    float4* __restrict__ out4, int n4)
{
    const int i = blockIdx.x * 256 + threadIdx.x;
    if (i >= n4) return;
    const int og = i & (OUTC / 4 - 1);
    const float4 r = R4[i];
    const float4 s = reinterpret_cast<const float4*>(sb)[og];
    const float4 b = reinterpret_cast<const float4*>(sb + OUTC)[og];
    float4 o;
    o.x = fmaxf(fmaf(s.x, r.x, b.x), 0.f);
    o.y = fmaxf(fmaf(s.y, r.y, b.y), 0.f);
    o.z = fmaxf(fmaf(s.z, r.z, b.z), 0.f);
    o.w = fmaxf(fmaf(s.w, r.w, b.w), 0.f);
    out4[i] = o;
}

// ---------------------------------------------------------------------------
extern "C" void kernel_launch(void* const* d_in, const int* in_sizes, int n_in,
                              void* d_out, int out_size, void* d_ws, size_t ws_size,
                              hipStream_t stream)
{
    const float* voxels = (const float*)d_in[0];
    const int*   coords = (const int*)d_in[1];
    const int*   npts   = (const int*)d_in[2];
    const float* W      = (const float*)d_in[3];
    const float* gamma  = (const float*)d_in[4];
    const float* beta   = (const float*)d_in[5];
    float*       out    = (float*)d_out;

    const int M = in_sizes[0] / (PP * 4);     // voxels is (M, P, 4); M even

    // ws layout (floats): partials[54*G1] | sb[128] | R[M*64]
    float* ws       = (float*)d_ws;
    float* partials = ws;
    float* sb       = ws + 54 * G1;
    float* R        = sb + 128;               // 16B aligned

    pfn_main<<<G1, B1, 0, stream>>>((const float4*)voxels, (const int4*)coords,
                                    npts, W, partials, R, M);
    pfn_finalize<<<1, 256, 0, stream>>>(partials, W, gamma, beta, sb,
                                        1.f / (float)(M * PP));
    const int n4 = M * (OUTC / 4);
    pfn_apply<<<(n4 + 255) / 256, 256, 0, stream>>>((const float4*)R, sb,
                                                    (float4*)out, n4);
}